// Round 2
// baseline (1202.888 us; speedup 1.0000x reference)
//
#include <hip/hip_runtime.h>
#include <cstdint>
#include <cstddef>

#define IN_DIM 768
#define OUT_DIM 128
#define N_NODES 100000
#define N_EDGES 1600000

typedef __bf16 bf16x8 __attribute__((ext_vector_type(8)));
typedef float f32x4 __attribute__((ext_vector_type(4)));

static __device__ __forceinline__ unsigned short f2bf(float f) {
  unsigned u = __builtin_bit_cast(unsigned, f);
  u += 0x7fffu + ((u >> 16) & 1u);      // round-to-nearest-even
  return (unsigned short)(u >> 16);
}
static __device__ __forceinline__ float bflo(unsigned u) {
  return __builtin_bit_cast(float, u << 16);
}
static __device__ __forceinline__ float bfhi(unsigned u) {
  return __builtin_bit_cast(float, u & 0xffff0000u);
}

// ---------------- CSR build ----------------

__global__ void deg_kernel(const int* __restrict__ src, const int* __restrict__ dst,
                           int* __restrict__ out_deg, int* __restrict__ in_deg) {
  int e = blockIdx.x * 256 + threadIdx.x;
  if (e < N_EDGES) {
    atomicAdd(&out_deg[src[e]], 1);
    atomicAdd(&in_deg[dst[e]], 1);
  }
}

__global__ void norm_kernel(const int* __restrict__ out_deg, float* __restrict__ norm_src) {
  int i = blockIdx.x * 256 + threadIdx.x;
  if (i < N_NODES) norm_src[i] = rsqrtf(fmaxf((float)out_deg[i], 1.0f));
}

// single-block exclusive scan of in_deg -> row_start[0..N_NODES]
__global__ void scan_kernel(const int* __restrict__ in_deg, int* __restrict__ row_start) {
  __shared__ int sm[256];
  __shared__ int carry_s;
  const int tid = threadIdx.x;
  if (tid == 0) carry_s = 0;
  __syncthreads();
  for (int base = 0; base < N_NODES; base += 1024) {
    int idx = base + tid * 4;
    int v0 = (idx + 0 < N_NODES) ? in_deg[idx + 0] : 0;
    int v1 = (idx + 1 < N_NODES) ? in_deg[idx + 1] : 0;
    int v2 = (idx + 2 < N_NODES) ? in_deg[idx + 2] : 0;
    int v3 = (idx + 3 < N_NODES) ? in_deg[idx + 3] : 0;
    int t0 = v0, t1 = t0 + v1, t2 = t1 + v2, t3 = t2 + v3;
    sm[tid] = t3;
    __syncthreads();
    for (int off = 1; off < 256; off <<= 1) {
      int x = (tid >= off) ? sm[tid - off] : 0;
      __syncthreads();
      sm[tid] += x;
      __syncthreads();
    }
    int base_sum = carry_s + (tid ? sm[tid - 1] : 0);
    if (idx + 0 < N_NODES) row_start[idx + 0] = base_sum;
    if (idx + 1 < N_NODES) row_start[idx + 1] = base_sum + t0;
    if (idx + 2 < N_NODES) row_start[idx + 2] = base_sum + t1;
    if (idx + 3 < N_NODES) row_start[idx + 3] = base_sum + t2;
    int total = sm[255];
    __syncthreads();
    if (tid == 0) carry_s += total;
    __syncthreads();
  }
  if (tid == 0) row_start[N_NODES] = carry_s;
}

__global__ void scatter_kernel(const int* __restrict__ src, const int* __restrict__ dst,
                               int* __restrict__ cursor, int* __restrict__ edge_src) {
  int e = blockIdx.x * 256 + threadIdx.x;
  if (e < N_EDGES) {
    int p = atomicAdd(&cursor[dst[e]], 1);
    edge_src[p] = src[e];
  }
}

// ---------------- GEMM1: h_bf16 = bf16((feat @ Wd + bd) * norm_src) ----------------
// BM=128, BN=128 (full), BK=32, 4 waves each 64x64, mfma 16x16x32 bf16

__global__ __launch_bounds__(256) void gemm1_kernel(
    const float* __restrict__ feat, const float* __restrict__ Wd,
    const float* __restrict__ bd, const float* __restrict__ norm_src,
    unsigned short* __restrict__ hbf) {
  __shared__ unsigned short a_lds[128][40];   // [m][k], pad 32->40
  __shared__ unsigned short b_lds[128][40];   // [n][k] (transposed Wd tile)
  const int tid = threadIdx.x;
  const int wave = tid >> 6;
  const int lane = tid & 63;
  const int m_off = (wave >> 1) * 64;
  const int n_off = (wave & 1) * 64;
  const int block_m = blockIdx.x * 128;
  const int fm = lane & 15;
  const int fk = (lane >> 4) * 8;

  f32x4 acc[4][4] = {};

  const int bn = tid & 127;   // B staging: n index
  const int bkq = tid >> 7;   // 0/1

  for (int k0 = 0; k0 < IN_DIM; k0 += 32) {
    // stage A tile 128x32 (fp32 -> bf16)
#pragma unroll
    for (int p = 0; p < 4; ++p) {
      int r = (tid >> 3) + p * 32;
      int c = (tid & 7) * 4;
      int gr = block_m + r;
      float4 v;
      if (gr < N_NODES) v = *(const float4*)(feat + (size_t)gr * IN_DIM + k0 + c);
      else v = make_float4(0.f, 0.f, 0.f, 0.f);
      ushort4 s;
      s.x = f2bf(v.x); s.y = f2bf(v.y); s.z = f2bf(v.z); s.w = f2bf(v.w);
      *(ushort4*)&a_lds[r][c] = s;
    }
    // stage B tile 32x128 transposed: b_lds[n][k] = Wd[k0+k][n]
#pragma unroll
    for (int p = 0; p < 4; ++p) {
      int k = bkq * 4 + p * 8;
      float x0 = Wd[(size_t)(k0 + k + 0) * OUT_DIM + bn];
      float x1 = Wd[(size_t)(k0 + k + 1) * OUT_DIM + bn];
      float x2 = Wd[(size_t)(k0 + k + 2) * OUT_DIM + bn];
      float x3 = Wd[(size_t)(k0 + k + 3) * OUT_DIM + bn];
      ushort4 s;
      s.x = f2bf(x0); s.y = f2bf(x1); s.z = f2bf(x2); s.w = f2bf(x3);
      *(ushort4*)&b_lds[bn][k] = s;
    }
    __syncthreads();
    bf16x8 af[4], bfr[4];
#pragma unroll
    for (int i = 0; i < 4; ++i)
      af[i] = *(const bf16x8*)&a_lds[m_off + i * 16 + fm][fk];
#pragma unroll
    for (int i = 0; i < 4; ++i)
      bfr[i] = *(const bf16x8*)&b_lds[n_off + i * 16 + fm][fk];
#pragma unroll
    for (int mi = 0; mi < 4; ++mi)
#pragma unroll
      for (int ni = 0; ni < 4; ++ni)
        acc[mi][ni] = __builtin_amdgcn_mfma_f32_16x16x32_bf16(af[mi], bfr[ni], acc[mi][ni], 0, 0, 0);
    __syncthreads();
  }
  // epilogue: (acc + bd[col]) * norm_src[row] -> bf16
  const int fr = (lane >> 4) * 4;
#pragma unroll
  for (int mi = 0; mi < 4; ++mi) {
#pragma unroll
    for (int r = 0; r < 4; ++r) {
      int row = block_m + m_off + mi * 16 + fr + r;
      if (row < N_NODES) {
        float ns = norm_src[row];
#pragma unroll
        for (int ni = 0; ni < 4; ++ni) {
          int col = n_off + ni * 16 + fm;
          float val = (acc[mi][ni][r] + bd[col]) * ns;
          hbf[(size_t)row * OUT_DIM + col] = f2bf(val);
        }
      }
    }
  }
}

// ---------------- aggregation: one wave per dst node ----------------

__global__ __launch_bounds__(256) void agg_kernel(
    const unsigned short* __restrict__ hbf, const int* __restrict__ row_start,
    const int* __restrict__ edge_src, unsigned short* __restrict__ aggb) {
  const int wave = threadIdx.x >> 6;
  const int lane = threadIdx.x & 63;
  const int v = blockIdx.x * 4 + wave;
  if (v >= N_NODES) return;
  const int beg = row_start[v];
  const int end = row_start[v + 1];
  const unsigned* hp = (const unsigned*)hbf;  // 64 uints per node row (128 bf16)
  float a0 = 0.f, a1 = 0.f;
  for (int e = beg; e < end; ++e) {
    int s = edge_src[e];
    unsigned u = hp[(size_t)s * 64 + lane];
    a0 += bflo(u);
    a1 += bfhi(u);
  }
  float nd = rsqrtf(fmaxf((float)(end - beg), 1.0f));
  a0 *= nd; a1 *= nd;
  unsigned o = (unsigned)f2bf(a0) | ((unsigned)f2bf(a1) << 16);
  ((unsigned*)aggb)[(size_t)v * 64 + lane] = o;
}

// ---------------- fold Wg@Wu and bg@Wu+bu ----------------

__global__ void wgu_kernel(const float* __restrict__ Wg, const float* __restrict__ Wu,
                           unsigned short* __restrict__ WguT) {
  int i = blockIdx.x * 256 + threadIdx.x;     // over 128*768
  if (i >= 128 * 768) return;
  int r = i / 768, c = i % 768;
  float s = 0.f;
  for (int k = 0; k < 128; ++k) s += Wg[r * 128 + k] * Wu[(size_t)k * 768 + c];
  WguT[(size_t)c * 128 + r] = f2bf(s);        // stored transposed: [n=768][k=128]
}

__global__ void bgu_kernel(const float* __restrict__ bg, const float* __restrict__ Wu,
                           const float* __restrict__ bu, float* __restrict__ bgu) {
  int c = blockIdx.x * 256 + threadIdx.x;
  if (c >= 768) return;
  float s = bu[c];
  for (int k = 0; k < 128; ++k) s += bg[k] * Wu[(size_t)k * 768 + c];
  bgu[c] = s;
}

// ---------------- GEMM3: out = agg_bf16 @ Wgu + bgu (fp32 out) ----------------
// BM=128, BN=128, K=128 (two 64-wide stages), 4 waves each 64x64

__global__ __launch_bounds__(256) void gemm3_kernel(
    const unsigned short* __restrict__ aggb, const unsigned short* __restrict__ WguT,
    const float* __restrict__ bgu, float* __restrict__ out) {
  __shared__ unsigned short a_lds[128][72];   // [m][k], pad 64->72
  __shared__ unsigned short b_lds[128][72];   // [n][k]
  const int tid = threadIdx.x;
  const int wave = tid >> 6;
  const int lane = tid & 63;
  const int m_off = (wave >> 1) * 64;
  const int n_off = (wave & 1) * 64;
  const int block_m = blockIdx.x * 128;
  const int block_n = blockIdx.y * 128;
  const int fm = lane & 15;
  const int fq = lane >> 4;

  f32x4 acc[4][4] = {};

  for (int k0 = 0; k0 < 128; k0 += 64) {
    // stage A tile 128 rows x 64 bf16 = 128 x 8 uint4 chunks = 1024 chunks
#pragma unroll
    for (int p = 0; p < 4; ++p) {
      int idx = tid + p * 256;        // [0,1024)
      int r = idx >> 3, ch = idx & 7;
      int gr = block_m + r;
      uint4 v;
      if (gr < N_NODES) v = *(const uint4*)(aggb + (size_t)gr * 128 + k0 + ch * 8);
      else v = make_uint4(0u, 0u, 0u, 0u);
      *(uint4*)&a_lds[r][ch * 8] = v;
    }
    // stage B tile 128 n-rows x 64 bf16
#pragma unroll
    for (int p = 0; p < 4; ++p) {
      int idx = tid + p * 256;        // [0,1024)
      int n = idx >> 3, ch = idx & 7;
      uint4 v = *(const uint4*)(WguT + (size_t)(block_n + n) * 128 + k0 + ch * 8);
      *(uint4*)&b_lds[n][ch * 8] = v;
    }
    __syncthreads();
#pragma unroll
    for (int ks = 0; ks < 64; ks += 32) {
      bf16x8 af[4], bfr[4];
      int kc = ks + fq * 8;
#pragma unroll
      for (int i = 0; i < 4; ++i) af[i] = *(const bf16x8*)&a_lds[m_off + i * 16 + fm][kc];
#pragma unroll
      for (int i = 0; i < 4; ++i) bfr[i] = *(const bf16x8*)&b_lds[n_off + i * 16 + fm][kc];
#pragma unroll
      for (int mi = 0; mi < 4; ++mi)
#pragma unroll
        for (int ni = 0; ni < 4; ++ni)
          acc[mi][ni] = __builtin_amdgcn_mfma_f32_16x16x32_bf16(af[mi], bfr[ni], acc[mi][ni], 0, 0, 0);
    }
    __syncthreads();
  }
  const int fr = fq * 4;
#pragma unroll
  for (int mi = 0; mi < 4; ++mi) {
#pragma unroll
    for (int r = 0; r < 4; ++r) {
      int row = block_m + m_off + mi * 16 + fr + r;
      if (row < N_NODES) {
#pragma unroll
        for (int ni = 0; ni < 4; ++ni) {
          int col = block_n + n_off + ni * 16 + fm;
          out[(size_t)row * IN_DIM + col] = acc[mi][ni][r] + bgu[col];
        }
      }
    }
  }
}

// ---------------- launch ----------------

extern "C" void kernel_launch(void* const* d_in, const int* in_sizes, int n_in,
                              void* d_out, int out_size, void* d_ws, size_t ws_size,
                              hipStream_t stream) {
  (void)in_sizes; (void)n_in; (void)out_size; (void)ws_size;
  const float* feat = (const float*)d_in[0];
  const float* Wd   = (const float*)d_in[1];
  const float* bd   = (const float*)d_in[2];
  const float* Wg   = (const float*)d_in[3];
  const float* bg   = (const float*)d_in[4];
  const float* Wu   = (const float*)d_in[5];
  const float* bu   = (const float*)d_in[6];
  const int*   src  = (const int*)d_in[7];
  const int*   dst  = (const int*)d_in[8];
  float* out = (float*)d_out;

  char* ws = (char*)d_ws;
  unsigned short* hbf       = (unsigned short*)(ws + 0);          // 25,600,000
  unsigned short* aggb      = (unsigned short*)(ws + 25600000);   // 25,600,000
  int*            edge_srcs = (int*)(ws + 51200000);              //  6,400,000
  int*            out_deg   = (int*)(ws + 57600000);              //    400,000
  int*            in_deg    = (int*)(ws + 58000000);              //    400,000
  int*            row_start = (int*)(ws + 58400000);              //    400,004
  int*            cursor    = (int*)(ws + 58800128);              //    400,000
  float*          norm_src  = (float*)(ws + 59200128);            //    400,000
  unsigned short* WguT      = (unsigned short*)(ws + 59600128);   //    196,608
  float*          bgu       = (float*)(ws + 59796736);            //      3,072

  // zero both degree arrays (contiguous 800,000 B)
  hipMemsetAsync(out_deg, 0, 800000, stream);
  deg_kernel<<<(N_EDGES + 255) / 256, 256, 0, stream>>>(src, dst, out_deg, in_deg);
  norm_kernel<<<(N_NODES + 255) / 256, 256, 0, stream>>>(out_deg, norm_src);
  scan_kernel<<<1, 256, 0, stream>>>(in_deg, row_start);
  hipMemcpyAsync(cursor, row_start, (size_t)N_NODES * sizeof(int),
                 hipMemcpyDeviceToDevice, stream);
  scatter_kernel<<<(N_EDGES + 255) / 256, 256, 0, stream>>>(src, dst, cursor, edge_srcs);
  gemm1_kernel<<<(N_NODES + 127) / 128, 256, 0, stream>>>(feat, Wd, bd, norm_src, hbf);
  agg_kernel<<<(N_NODES + 3) / 4, 256, 0, stream>>>(hbf, row_start, edge_srcs, aggb);
  wgu_kernel<<<(128 * 768 + 255) / 256, 256, 0, stream>>>(Wg, Wu, WguT);
  bgu_kernel<<<3, 256, 0, stream>>>(bg, Wu, bu, bgu);
  gemm3_kernel<<<dim3((N_NODES + 127) / 128, 6), 256, 0, stream>>>(aggb, WguT, bgu, out);
}